// Round 1
// baseline (9129.097 us; speedup 1.0000x reference)
//
#include <hip/hip_runtime.h>
#include <hip/hip_bf16.h>
#include <math.h>

// Problem constants
#define BB 128
#define TT 1024
#define DD 256
#define HH 256
// flattened rows of x: B*T
#define MM (BB * TT)
// concatenated projection width: 3*H
#define NN3 768

static __device__ __forceinline__ float bf2f(unsigned int u16) {
    return __uint_as_float(u16 << 16);
}
static __device__ __forceinline__ unsigned short f2bf(float f) {
    unsigned int u = __float_as_uint(f);
    unsigned int r = u + 0x7FFFu + ((u >> 16) & 1u);  // RNE
    return (unsigned short)(r >> 16);
}

// ---------------------------------------------------------------------------
// Phase 0: pack U_z,U_r,U_h (fp32 [256x256] row-major, [k][j]) into bf16
// k-pair-packed dwords: upk[g*32768 + k2*256 + j] = (bf16 U[2k2][j]) |
// (bf16 U[2k2+1][j] << 16).  3*128*256 = 98304 dwords = 384 KB.
// ---------------------------------------------------------------------------
__global__ __launch_bounds__(256) void pack_u_kernel(
    const float* __restrict__ Uz, const float* __restrict__ Ur,
    const float* __restrict__ Uh, unsigned int* __restrict__ upk)
{
    int idx = blockIdx.x * 256 + threadIdx.x;  // 0..98303
    int g   = idx >> 15;
    int rem = idx & 32767;
    int k2  = rem >> 8;
    int j   = rem & 255;
    const float* U = (g == 0) ? Uz : ((g == 1) ? Ur : Uh);
    float lo = U[(2 * k2) * HH + j];
    float hi = U[(2 * k2 + 1) * HH + j];
    upk[idx] = (unsigned int)f2bf(lo) | ((unsigned int)f2bf(hi) << 16);
}

// ---------------------------------------------------------------------------
// Phase 1: xw[m][n] = bf16( sum_k x[m][k] * Wcat[k][n] + bcat[n] )
//   m in [0,131072), n in [0,768) where n<256 -> W_z, <512 -> W_r, else W_h.
// Tiled fp32 GEMM: 64x64 tile per 256-thread block, KT=16.
// ---------------------------------------------------------------------------
#define KT 16
__global__ __launch_bounds__(256) void xproj_kernel(
    const float* __restrict__ x,
    const float* __restrict__ Wz, const float* __restrict__ Wr,
    const float* __restrict__ Wh,
    const float* __restrict__ bz, const float* __restrict__ br,
    const float* __restrict__ bh,
    unsigned short* __restrict__ xw)
{
    __shared__ float As[KT][64 + 8];   // [k][m]
    __shared__ float Bs[KT][64 + 8];   // [k][n]

    const int tid = threadIdx.x;
    const int m0 = blockIdx.y * 64;
    const int n0 = blockIdx.x * 64;    // gridDim.x = 12

    const float* W    = (n0 < 256) ? Wz : (n0 < 512 ? Wr : Wh);
    const float* bias = (n0 < 256) ? bz : (n0 < 512 ? br : bh);
    const int nc0 = n0 & 255;          // column offset within the gate matrix

    // A-load mapping: 64 m-rows x 16 k, 4 consecutive k per thread
    const int lm  = tid >> 2;          // 0..63
    const int lk4 = (tid & 3) * 4;     // 0,4,8,12
    // B-load mapping: 16 k-rows x 64 n, 4 k-rows per thread (same n)
    const int bn  = tid & 63;          // 0..63
    const int bkq = tid >> 6;          // 0..3

    const int tm = tid >> 4;           // 0..15 -> rows tm*4..tm*4+3
    const int tn = tid & 15;           // 0..15 -> cols tn*4..tn*4+3

    float acc[4][4];
#pragma unroll
    for (int i = 0; i < 4; i++)
#pragma unroll
        for (int jj = 0; jj < 4; jj++) acc[i][jj] = 0.f;

    for (int k0 = 0; k0 < DD; k0 += KT) {
        const float4 av = *(const float4*)&x[(size_t)(m0 + lm) * DD + k0 + lk4];
        float bvv[4];
#pragma unroll
        for (int s = 0; s < 4; s++)
            bvv[s] = W[(size_t)(k0 + bkq * 4 + s) * HH + nc0 + bn];

        __syncthreads();  // previous tile's compute reads done
        As[lk4 + 0][lm] = av.x;
        As[lk4 + 1][lm] = av.y;
        As[lk4 + 2][lm] = av.z;
        As[lk4 + 3][lm] = av.w;
#pragma unroll
        for (int s = 0; s < 4; s++) Bs[bkq * 4 + s][bn] = bvv[s];
        __syncthreads();

#pragma unroll
        for (int k = 0; k < KT; k++) {
            float4 a  = *(const float4*)&As[k][tm * 4];
            float4 bv = *(const float4*)&Bs[k][tn * 4];
            acc[0][0] += a.x * bv.x; acc[0][1] += a.x * bv.y;
            acc[0][2] += a.x * bv.z; acc[0][3] += a.x * bv.w;
            acc[1][0] += a.y * bv.x; acc[1][1] += a.y * bv.y;
            acc[1][2] += a.y * bv.z; acc[1][3] += a.y * bv.w;
            acc[2][0] += a.z * bv.x; acc[2][1] += a.z * bv.y;
            acc[2][2] += a.z * bv.z; acc[2][3] += a.z * bv.w;
            acc[3][0] += a.w * bv.x; acc[3][1] += a.w * bv.y;
            acc[3][2] += a.w * bv.z; acc[3][3] += a.w * bv.w;
        }
    }

    float bvals[4];
#pragma unroll
    for (int jj = 0; jj < 4; jj++) bvals[jj] = bias[nc0 + tn * 4 + jj];

#pragma unroll
    for (int i = 0; i < 4; i++) {
        int m = m0 + tm * 4 + i;
        ushort4 pk;
        pk.x = f2bf(acc[i][0] + bvals[0]);
        pk.y = f2bf(acc[i][1] + bvals[1]);
        pk.z = f2bf(acc[i][2] + bvals[2]);
        pk.w = f2bf(acc[i][3] + bvals[3]);
        *(ushort4*)&xw[(size_t)m * NN3 + n0 + tn * 4] = pk;
    }
}

// ---------------------------------------------------------------------------
// Phase 2: sequential GRU recurrence. One block per batch (128 blocks),
// 256 threads = one output column j each. h state in LDS (double-buffered),
// U streamed from L2 as packed-bf16 pairs, fp32 accumulation.
// ---------------------------------------------------------------------------
__global__ __launch_bounds__(256) void gru_rec_kernel(
    const unsigned short* __restrict__ xw,
    const unsigned int* __restrict__ upk,
    float* __restrict__ out)
{
    __shared__ float hbuf[2][HH];
    __shared__ float rhs[HH];

    const int b = blockIdx.x;
    const int j = threadIdx.x;

    const unsigned int* __restrict__ Uz = upk;
    const unsigned int* __restrict__ Ur = upk + 32768;
    const unsigned int* __restrict__ Uh = upk + 65536;

    hbuf[0][j] = 0.f;
    __syncthreads();
    int cur = 0;

    const unsigned short* xrow = xw + (size_t)b * TT * NN3;

    for (int t = 0; t < TT; t++) {
        const unsigned short* xt = xrow + (size_t)t * NN3;
        float az = bf2f(xt[j]);
        float ar = bf2f(xt[256 + j]);
        float ah = bf2f(xt[512 + j]);

        const float* hc = hbuf[cur];

#pragma unroll 8
        for (int k2 = 0; k2 < 128; k2++) {
            float2 hp = *(const float2*)&hc[2 * k2];     // LDS broadcast
            unsigned int uz = Uz[k2 * 256 + j];
            unsigned int ur = Ur[k2 * 256 + j];
            az += hp.x * bf2f(uz & 0xffffu) + hp.y * bf2f(uz >> 16);
            ar += hp.x * bf2f(ur & 0xffffu) + hp.y * bf2f(ur >> 16);
        }
        float z = fminf(1.f, fmaxf(0.f, 0.2f * az + 0.5f));
        float r = fminf(1.f, fmaxf(0.f, 0.2f * ar + 0.5f));
        float hj = hc[j];
        rhs[j] = r * hj;
        __syncthreads();

#pragma unroll 8
        for (int k2 = 0; k2 < 128; k2++) {
            float2 rp = *(const float2*)&rhs[2 * k2];
            unsigned int uh = Uh[k2 * 256 + j];
            ah += rp.x * bf2f(uh & 0xffffu) + rp.y * bf2f(uh >> 16);
        }
        float hh = tanhf(ah);
        float hn = z * hj + (1.f - z) * hh;

        hbuf[cur ^ 1][j] = hn;
        cur ^= 1;
        __syncthreads();
    }

    out[(size_t)b * HH + j] = hbuf[cur][j];
}

// ---------------------------------------------------------------------------
extern "C" void kernel_launch(void* const* d_in, const int* in_sizes, int n_in,
                              void* d_out, int out_size, void* d_ws, size_t ws_size,
                              hipStream_t stream) {
    const float* x  = (const float*)d_in[0];
    const float* Wz = (const float*)d_in[1];
    const float* Wr = (const float*)d_in[2];
    const float* Wh = (const float*)d_in[3];
    const float* Uz = (const float*)d_in[4];
    const float* Ur = (const float*)d_in[5];
    const float* Uh = (const float*)d_in[6];
    const float* bz = (const float*)d_in[7];
    const float* br = (const float*)d_in[8];
    const float* bh = (const float*)d_in[9];
    float* out = (float*)d_out;

    // workspace layout: [xw: 131072*768 bf16 = 192 MiB][upk: 98304 dwords]
    unsigned short* xw = (unsigned short*)d_ws;
    unsigned int* upk =
        (unsigned int*)((char*)d_ws + (size_t)MM * NN3 * sizeof(unsigned short));

    pack_u_kernel<<<98304 / 256, 256, 0, stream>>>(Uz, Ur, Uh, upk);

    dim3 g1(NN3 / 64, MM / 64);  // 12 x 2048
    xproj_kernel<<<g1, 256, 0, stream>>>(x, Wz, Wr, Wh, bz, br, bh, xw);

    gru_rec_kernel<<<BB, 256, 0, stream>>>(xw, upk, out);
}

// Round 2
// 7067.670 us; speedup vs baseline: 1.2917x; 1.2917x over previous
//
#include <hip/hip_runtime.h>
#include <hip/hip_bf16.h>
#include <math.h>

// Problem constants
#define BB 128
#define TT 1024
#define DD 256
#define HH 256
#define MM (BB * TT)
#define NN3 768

typedef __attribute__((ext_vector_type(8))) short short8;
typedef __attribute__((ext_vector_type(4))) float f32x4;

static __device__ __forceinline__ float bf2f(unsigned int u16) {
    return __uint_as_float(u16 << 16);
}
static __device__ __forceinline__ unsigned short f2bf(float f) {
    unsigned int u = __float_as_uint(f);
    unsigned int r = u + 0x7FFFu + ((u >> 16) & 1u);  // RNE
    return (unsigned short)(r >> 16);
}

// Workgroup barrier that does NOT drain vmcnt (register prefetch stays in
// flight); lgkmcnt(0) makes LDS writes visible before the barrier.
static __device__ __forceinline__ void barrier_lgkm() {
    asm volatile("s_waitcnt lgkmcnt(0)\n\ts_barrier" ::: "memory");
}

// ---------------------------------------------------------------------------
// Phase 1: xw = bf16(x @ [Wz|Wr|Wh] + b), written in a lane-major layout the
// recurrence consumes with tiny vector loads.
// Layout per (t, gate, bid):  base = ((t*3+g)*8 + bid)*4096
//   g<2 : base + ((brow*16 + (c&15))*4 + (c>>6))*4 + ((c>>4)&3)
//   g==2: base + (brow*16 + (c&15))*16 + (c>>4)
// where b = bid*16 + brow, c = column within the gate (0..255).
// ---------------------------------------------------------------------------
#define KT 16
__global__ __launch_bounds__(256) void xproj_kernel(
    const float* __restrict__ x,
    const float* __restrict__ Wz, const float* __restrict__ Wr,
    const float* __restrict__ Wh,
    const float* __restrict__ bz, const float* __restrict__ br,
    const float* __restrict__ bh,
    unsigned short* __restrict__ xw)
{
    __shared__ float As[KT][64 + 8];   // [k][m]
    __shared__ float Bs[KT][64 + 8];   // [k][n]

    const int tid = threadIdx.x;
    const int m0 = blockIdx.y * 64;
    const int n0 = blockIdx.x * 64;    // gridDim.x = 12

    const float* W    = (n0 < 256) ? Wz : (n0 < 512 ? Wr : Wh);
    const float* bias = (n0 < 256) ? bz : (n0 < 512 ? br : bh);
    const int nc0 = n0 & 255;
    const int g   = n0 >> 8;           // gate id 0/1/2

    const int lm  = tid >> 2;
    const int lk4 = (tid & 3) * 4;
    const int bn  = tid & 63;
    const int bkq = tid >> 6;

    const int tm = tid >> 4;
    const int tn = tid & 15;

    float acc[4][4];
#pragma unroll
    for (int i = 0; i < 4; i++)
#pragma unroll
        for (int jj = 0; jj < 4; jj++) acc[i][jj] = 0.f;

    for (int k0 = 0; k0 < DD; k0 += KT) {
        const float4 av = *(const float4*)&x[(size_t)(m0 + lm) * DD + k0 + lk4];
        float bvv[4];
#pragma unroll
        for (int s = 0; s < 4; s++)
            bvv[s] = W[(size_t)(k0 + bkq * 4 + s) * HH + nc0 + bn];

        __syncthreads();
        As[lk4 + 0][lm] = av.x;
        As[lk4 + 1][lm] = av.y;
        As[lk4 + 2][lm] = av.z;
        As[lk4 + 3][lm] = av.w;
#pragma unroll
        for (int s = 0; s < 4; s++) Bs[bkq * 4 + s][bn] = bvv[s];
        __syncthreads();

#pragma unroll
        for (int k = 0; k < KT; k++) {
            float4 a  = *(const float4*)&As[k][tm * 4];
            float4 bv = *(const float4*)&Bs[k][tn * 4];
            acc[0][0] += a.x * bv.x; acc[0][1] += a.x * bv.y;
            acc[0][2] += a.x * bv.z; acc[0][3] += a.x * bv.w;
            acc[1][0] += a.y * bv.x; acc[1][1] += a.y * bv.y;
            acc[1][2] += a.y * bv.z; acc[1][3] += a.y * bv.w;
            acc[2][0] += a.z * bv.x; acc[2][1] += a.z * bv.y;
            acc[2][2] += a.z * bv.z; acc[2][3] += a.z * bv.w;
            acc[3][0] += a.w * bv.x; acc[3][1] += a.w * bv.y;
            acc[3][2] += a.w * bv.z; acc[3][3] += a.w * bv.w;
        }
    }

    float bvals[4];
#pragma unroll
    for (int jj = 0; jj < 4; jj++) bvals[jj] = bias[nc0 + tn * 4 + jj];

#pragma unroll
    for (int i = 0; i < 4; i++) {
        int m = m0 + tm * 4 + i;
        int b = m >> 10, t = m & 1023;
        int bid = b >> 4, brow = b & 15;
        size_t gbase = ((size_t)(t * 3 + g) * 8 + bid) * 4096;
#pragma unroll
        for (int jj = 0; jj < 4; jj++) {
            int c = nc0 + tn * 4 + jj;
            unsigned short v = f2bf(acc[i][jj] + bvals[jj]);
            size_t idx;
            if (g < 2)
                idx = gbase + (size_t)(((brow * 16 + (c & 15)) * 4 + (c >> 6)) * 4
                                       + ((c >> 4) & 3));
            else
                idx = gbase + (size_t)((brow * 16 + (c & 15)) * 16 + (c >> 4));
            xw[idx] = v;
        }
    }
}

// ---------------------------------------------------------------------------
// Phase 2: persistent-register MFMA GRU recurrence.
// 8 blocks x 512 threads (8 waves). Block handles 16 batches. Each wave holds
// B-fragments for 64 cols of its z/r gate (128 VGPRs) + 32 cols of U_h (64).
// h state in LDS: fp32 master hF + bf16 A-layout copy hA.
// ---------------------------------------------------------------------------
__global__ __launch_bounds__(512, 2) void gru_rec_kernel(
    const unsigned short* __restrict__ xw,
    const float* __restrict__ Uz, const float* __restrict__ Ur,
    const float* __restrict__ Uh,
    float* __restrict__ out)
{
    __shared__ short hA[16][264];    // h, bf16, [batch-row][k], +8 pad
    __shared__ short rhA[16][264];   // r*h, bf16, same layout
    __shared__ float hF[16][257];    // fp32 h master
    __shared__ float zS[16][257];    // z gate values

    const int tid  = threadIdx.x;
    const int lane = tid & 63;
    const int wv   = tid >> 6;       // 0..7
    const int nq   = lane & 15;      // MFMA 16-dim index
    const int kq   = lane >> 4;      // quad
    const int bid  = blockIdx.x;     // 0..7

    // ---- load persistent weight fragments ----
    const float* Uzr = (wv < 4) ? Uz : Ur;
    const int n0  = (wv & 3) * 64;   // z/r cols owned by this wave
    const int m0h = wv * 32;         // Uh cols owned by this wave

    short8 wzr[4][8];                // [n-tile][k-chunk]
#pragma unroll
    for (int nt = 0; nt < 4; ++nt)
#pragma unroll
        for (int c = 0; c < 8; ++c) {
            short8 f;
#pragma unroll
            for (int j = 0; j < 8; ++j)
                f[j] = (short)f2bf(
                    Uzr[(size_t)(c * 32 + kq * 8 + j) * HH + n0 + nt * 16 + nq]);
            wzr[nt][c] = f;
        }
    short8 wh[2][8];
#pragma unroll
    for (int ht = 0; ht < 2; ++ht)
#pragma unroll
        for (int c = 0; c < 8; ++c) {
            short8 f;
#pragma unroll
            for (int j = 0; j < 8; ++j)
                f[j] = (short)f2bf(
                    Uh[(size_t)(c * 32 + kq * 8 + j) * HH + m0h + ht * 16 + nq]);
            wh[ht][c] = f;
        }

    // ---- zero h ----
    for (int idx = tid; idx < 16 * 264; idx += 512) ((short*)hA)[idx] = 0;
    for (int idx = tid; idx < 16 * 257; idx += 512) ((float*)hF)[idx] = 0.f;
    __syncthreads();

    // ---- per-lane x offsets (elements) ----
    const int g01 = wv >> 2;
    const int wblk = wv & 3;
    int off01[4], off2[4];
#pragma unroll
    for (int i = 0; i < 4; ++i) {
        int row = kq * 4 + i;
        off01[i] = g01 * 8 * 4096 + bid * 4096 + ((row * 16 + nq) * 4 + wblk) * 4;
        off2[i]  = 2 * 8 * 4096  + bid * 4096 + (row * 16 + nq) * 16 + 2 * wv;
    }

    auto load_x = [&](int t, uint2 (&xzr)[4], unsigned int (&xh)[4]) {
        const unsigned short* base = xw + (size_t)t * 98304;  // 3*8*4096
#pragma unroll
        for (int i = 0; i < 4; ++i) {
            xzr[i] = *(const uint2*)(base + off01[i]);
            xh[i]  = *(const unsigned int*)(base + off2[i]);
        }
    };

    uint2 xzrA[4], xzrB[4];
    unsigned int xhA_[4], xhB_[4];

    auto step = [&](int t, uint2 (&xzrC)[4], unsigned int (&xhC)[4],
                    uint2 (&xzrN)[4], unsigned int (&xhN)[4]) {
        // prefetch next step's x into registers (consumed next call)
        int tn2 = (t + 1 < TT) ? (t + 1) : (TT - 1);
        load_x(tn2, xzrN, xhN);

        // ---- phase A: z,r pre-activations ----
        f32x4 acc[4];
#pragma unroll
        for (int nt = 0; nt < 4; ++nt) acc[nt] = (f32x4){0.f, 0.f, 0.f, 0.f};
#pragma unroll
        for (int c = 0; c < 8; ++c) {
            short8 af = *(const short8*)&hA[nq][c * 32 + kq * 8];
#pragma unroll
            for (int nt = 0; nt < 4; ++nt)
                acc[nt] = __builtin_amdgcn_mfma_f32_16x16x32_bf16(
                    af, wzr[nt][c], acc[nt], 0, 0, 0);
        }
        if (wv < 4) {  // z-waves
#pragma unroll
            for (int nt = 0; nt < 4; ++nt) {
                int col = n0 + nt * 16 + nq;
#pragma unroll
                for (int i = 0; i < 4; ++i) {
                    int row = kq * 4 + i;
                    unsigned int w32 = (nt < 2) ? xzrC[i].x : xzrC[i].y;
                    unsigned int xv = (nt & 1) ? (w32 >> 16) : (w32 & 0xffffu);
                    float a = acc[nt][i] + bf2f(xv);
                    float s = fminf(1.f, fmaxf(0.f, __builtin_fmaf(0.2f, a, 0.5f)));
                    zS[row][col] = s;
                }
            }
        } else {       // r-waves
#pragma unroll
            for (int nt = 0; nt < 4; ++nt) {
                int col = n0 + nt * 16 + nq;
#pragma unroll
                for (int i = 0; i < 4; ++i) {
                    int row = kq * 4 + i;
                    unsigned int w32 = (nt < 2) ? xzrC[i].x : xzrC[i].y;
                    unsigned int xv = (nt & 1) ? (w32 >> 16) : (w32 & 0xffffu);
                    float a = acc[nt][i] + bf2f(xv);
                    float s = fminf(1.f, fmaxf(0.f, __builtin_fmaf(0.2f, a, 0.5f)));
                    rhA[row][col] = (short)f2bf(s * hF[row][col]);
                }
            }
        }
        barrier_lgkm();

        // ---- phase B: candidate + state update ----
        f32x4 ah0 = (f32x4){0.f, 0.f, 0.f, 0.f};
        f32x4 ah1 = (f32x4){0.f, 0.f, 0.f, 0.f};
#pragma unroll
        for (int c = 0; c < 8; ++c) {
            short8 af = *(const short8*)&rhA[nq][c * 32 + kq * 8];
            ah0 = __builtin_amdgcn_mfma_f32_16x16x32_bf16(af, wh[0][c], ah0, 0, 0, 0);
            ah1 = __builtin_amdgcn_mfma_f32_16x16x32_bf16(af, wh[1][c], ah1, 0, 0, 0);
        }
#pragma unroll
        for (int ht = 0; ht < 2; ++ht) {
            int col = m0h + ht * 16 + nq;
#pragma unroll
            for (int i = 0; i < 4; ++i) {
                int row = kq * 4 + i;
                unsigned int xv = ht ? (xhC[i] >> 16) : (xhC[i] & 0xffffu);
                float a = (ht ? ah1[i] : ah0[i]) + bf2f(xv);
                a = fminf(15.f, fmaxf(-15.f, a));
                float e  = __expf(2.f * a);
                float hh = (e - 1.f) * __builtin_amdgcn_rcpf(e + 1.f);  // tanh
                float z  = zS[row][col];
                float ho = hF[row][col];
                float hn = __builtin_fmaf(z, ho - hh, hh);  // z*ho + (1-z)*hh
                hF[row][col] = hn;
                hA[row][col] = (short)f2bf(hn);
            }
        }
        barrier_lgkm();
    };

    load_x(0, xzrA, xhA_);
    for (int t = 0; t < TT; t += 2) {
        step(t,     xzrA, xhA_, xzrB, xhB_);
        step(t + 1, xzrB, xhB_, xzrA, xhA_);
    }

    for (int idx = tid; idx < 16 * 256; idx += 512) {
        int r = idx >> 8, c = idx & 255;
        out[(size_t)(bid * 16 + r) * HH + c] = hF[r][c];
    }
}

// ---------------------------------------------------------------------------
extern "C" void kernel_launch(void* const* d_in, const int* in_sizes, int n_in,
                              void* d_out, int out_size, void* d_ws, size_t ws_size,
                              hipStream_t stream) {
    const float* x  = (const float*)d_in[0];
    const float* Wz = (const float*)d_in[1];
    const float* Wr = (const float*)d_in[2];
    const float* Wh = (const float*)d_in[3];
    const float* Uz = (const float*)d_in[4];
    const float* Ur = (const float*)d_in[5];
    const float* Uh = (const float*)d_in[6];
    const float* bz = (const float*)d_in[7];
    const float* br = (const float*)d_in[8];
    const float* bh = (const float*)d_in[9];
    float* out = (float*)d_out;

    unsigned short* xw = (unsigned short*)d_ws;  // 192 MiB

    dim3 g1(NN3 / 64, MM / 64);  // 12 x 2048
    xproj_kernel<<<g1, 256, 0, stream>>>(x, Wz, Wr, Wh, bz, br, bh, xw);

    gru_rec_kernel<<<8, 512, 0, stream>>>(xw, Uz, Ur, Uh, out);
}

// Round 3
// 3239.175 us; speedup vs baseline: 2.8183x; 2.1819x over previous
//
#include <hip/hip_runtime.h>
#include <hip/hip_bf16.h>
#include <math.h>

// Problem constants
#define BB 128
#define TT 1024
#define DD 256
#define HH 256
#define MM (BB * TT)
#define NN3 768

typedef __attribute__((ext_vector_type(8))) short short8;
typedef __attribute__((ext_vector_type(4))) float f32x4;
typedef __attribute__((address_space(1))) unsigned int gu32;
typedef __attribute__((address_space(3))) unsigned int lu32;

static __device__ __forceinline__ float bf2f(unsigned int u16) {
    return __uint_as_float(u16 << 16);
}
// RNE (used for weights, one-time)
static __device__ __forceinline__ unsigned short f2bf(float f) {
    unsigned int u = __float_as_uint(f);
    unsigned int r = u + 0x7FFFu + ((u >> 16) & 1u);
    return (unsigned short)(r >> 16);
}
// round-half-up, 2 ops (per-step activations; tie-bias negligible)
static __device__ __forceinline__ unsigned short f2bf_fast(float f) {
    return (unsigned short)((__float_as_uint(f) + 0x8000u) >> 16);
}

// barrier flavors: mid-step needs only LDS visibility (keep the async x-stage
// loads in flight); end-of-step drains vmcnt (stage issued ~1 step earlier).
static __device__ __forceinline__ void barrier_lgkm() {
    asm volatile("s_waitcnt lgkmcnt(0)\n\ts_barrier" ::: "memory");
}
static __device__ __forceinline__ void barrier_full() {
    asm volatile("s_waitcnt vmcnt(0) lgkmcnt(0)\n\ts_barrier" ::: "memory");
}

// ---------------------------------------------------------------------------
// Phase 1: xw = bf16(x @ [Wz|Wr|Wh] + b), written in recurrence-native layout.
// Per (t, bid) chunk of 12288 shorts (24576 B), element order [ti:48][lane:64][ii:4]:
//   ti   = gate*16 + (col>>4)        (global 16-col tile id)
//   lane = (brow>>2)*16 + (col&15)   (the MFMA lane that consumes it)
//   ii   = brow&3                    (C-fragment reg index / batch sub-row)
// where b = bid*16 + brow. The recurrence reads one ds_read_b64 per tile.
// ---------------------------------------------------------------------------
#define KT 16
__global__ __launch_bounds__(256) void xproj_kernel(
    const float* __restrict__ x,
    const float* __restrict__ Wz, const float* __restrict__ Wr,
    const float* __restrict__ Wh,
    const float* __restrict__ bz, const float* __restrict__ br,
    const float* __restrict__ bh,
    unsigned short* __restrict__ xw)
{
    __shared__ float As[KT][64 + 8];   // [k][m]
    __shared__ float Bs[KT][64 + 8];   // [k][n]

    const int tid = threadIdx.x;
    const int m0 = blockIdx.y * 64;
    const int n0 = blockIdx.x * 64;    // gridDim.x = 12

    const float* W    = (n0 < 256) ? Wz : (n0 < 512 ? Wr : Wh);
    const float* bias = (n0 < 256) ? bz : (n0 < 512 ? br : bh);
    const int nc0 = n0 & 255;
    const int g   = n0 >> 8;

    const int lm  = tid >> 2;
    const int lk4 = (tid & 3) * 4;
    const int bn  = tid & 63;
    const int bkq = tid >> 6;

    const int tm = tid >> 4;
    const int tn = tid & 15;

    float acc[4][4];
#pragma unroll
    for (int i = 0; i < 4; i++)
#pragma unroll
        for (int jj = 0; jj < 4; jj++) acc[i][jj] = 0.f;

    for (int k0 = 0; k0 < DD; k0 += KT) {
        const float4 av = *(const float4*)&x[(size_t)(m0 + lm) * DD + k0 + lk4];
        float bvv[4];
#pragma unroll
        for (int s = 0; s < 4; s++)
            bvv[s] = W[(size_t)(k0 + bkq * 4 + s) * HH + nc0 + bn];

        __syncthreads();
        As[lk4 + 0][lm] = av.x;
        As[lk4 + 1][lm] = av.y;
        As[lk4 + 2][lm] = av.z;
        As[lk4 + 3][lm] = av.w;
#pragma unroll
        for (int s = 0; s < 4; s++) Bs[bkq * 4 + s][bn] = bvv[s];
        __syncthreads();

#pragma unroll
        for (int k = 0; k < KT; k++) {
            float4 a  = *(const float4*)&As[k][tm * 4];
            float4 bv = *(const float4*)&Bs[k][tn * 4];
            acc[0][0] += a.x * bv.x; acc[0][1] += a.x * bv.y;
            acc[0][2] += a.x * bv.z; acc[0][3] += a.x * bv.w;
            acc[1][0] += a.y * bv.x; acc[1][1] += a.y * bv.y;
            acc[1][2] += a.y * bv.z; acc[1][3] += a.y * bv.w;
            acc[2][0] += a.z * bv.x; acc[2][1] += a.z * bv.y;
            acc[2][2] += a.z * bv.z; acc[2][3] += a.z * bv.w;
            acc[3][0] += a.w * bv.x; acc[3][1] += a.w * bv.y;
            acc[3][2] += a.w * bv.z; acc[3][3] += a.w * bv.w;
        }
    }

    float bvals[4];
#pragma unroll
    for (int jj = 0; jj < 4; jj++) bvals[jj] = bias[nc0 + tn * 4 + jj];

#pragma unroll
    for (int i = 0; i < 4; i++) {
        int m = m0 + tm * 4 + i;
        int b = m >> 10, t = m & 1023;
        int bid = b >> 4, brow = b & 15;
        size_t cbase = (size_t)(t * 8 + bid) * 12288;
        int lhi = (brow >> 2) * 16;   // kq*16
        int ii  = brow & 3;
#pragma unroll
        for (int jj = 0; jj < 4; jj++) {
            int c = nc0 + tn * 4 + jj;
            int ti = g * 16 + (c >> 4);
            int lane = lhi + (c & 15);
            xw[cbase + (size_t)(ti * 256 + lane * 4 + ii)] =
                f2bf(acc[i][jj] + bvals[jj]);
        }
    }
}

// ---------------------------------------------------------------------------
// Phase 2: persistent-register MFMA GRU recurrence.
// 8 blocks x 512 threads (8 waves, pinned 2 waves/EU -> 256 unified regs).
// Wave w owns gate-tiles {w, w+8} of z, r, and h (column-aligned): z and
// h_prev never leave registers. h (bf16 A-fragment) and r*h go through LDS.
// x staged per-step into an LDS double buffer via global_load_lds.
// ---------------------------------------------------------------------------
__global__ __launch_bounds__(512)
__attribute__((amdgpu_waves_per_eu(2, 2)))
void gru_rec_kernel(
    const unsigned short* __restrict__ xw,
    const float* __restrict__ Uz, const float* __restrict__ Ur,
    const float* __restrict__ Uh,
    float* __restrict__ out)
{
    __shared__ unsigned short xstage[2][12288];  // 2 x 24576 B
    __shared__ short hA[16][264];    // h bf16, stride 132 dw (conflict-free b128)
    __shared__ short rhA[16][264];   // r*h bf16, same layout

    const int tid  = threadIdx.x;
    const int lane = tid & 63;
    const int wv   = tid >> 6;       // 0..7
    const int nq   = lane & 15;
    const int kq   = lane >> 4;
    const int bid  = blockIdx.x;     // 0..7

    // ---- persistent weight fragments (192 VGPRs/lane) ----
    short8 wzr[4][8];   // tj 0,1 = Uz tiles {wv, wv+8}; tj 2,3 = Ur tiles
#pragma unroll
    for (int tj = 0; tj < 4; ++tj) {
        const float* U = (tj < 2) ? Uz : Ur;
        const int col0 = (wv + 8 * (tj & 1)) * 16;
#pragma unroll
        for (int c = 0; c < 8; ++c) {
            short8 f;
#pragma unroll
            for (int j = 0; j < 8; ++j)
                f[j] = (short)f2bf(U[(size_t)(c * 32 + kq * 8 + j) * HH + col0 + nq]);
            wzr[tj][c] = f;
        }
    }
    short8 wh[2][8];
#pragma unroll
    for (int tj = 0; tj < 2; ++tj) {
        const int col0 = (wv + 8 * tj) * 16;
#pragma unroll
        for (int c = 0; c < 8; ++c) {
            short8 f;
#pragma unroll
            for (int j = 0; j < 8; ++j)
                f[j] = (short)f2bf(Uh[(size_t)(c * 32 + kq * 8 + j) * HH + col0 + nq]);
            wh[tj][c] = f;
        }
    }

    // ---- init h ----
    for (int idx = tid; idx < 16 * 264; idx += 512) ((short*)hA)[idx] = 0;
    float hprev[8];   // [tj*4+i] : rows kq*4+i, col (wv+8tj)*16+nq
#pragma unroll
    for (int i = 0; i < 8; ++i) hprev[i] = 0.f;

    // ---- async x staging (3 x 16B-wide global_load_lds per wave per step) ----
    auto stage = [&](int t, int buf) {
        const char* gsrc = (const char*)(xw + (size_t)(t * 8 + bid) * 12288);
        char* lbase = (char*)&xstage[buf][0];
        int woff = wv * 3072;
#pragma unroll
        for (int ld = 0; ld < 3; ++ld) {
            int off = woff + ld * 1024;
            __builtin_amdgcn_global_load_lds(
                (const gu32*)(gsrc + off + lane * 16),
                (lu32*)(lbase + off), 16, 0, 0);
        }
    };

    stage(0, 0);
    barrier_full();   // stage 0 landed everywhere; hA zeros visible

    const int tiz = wv;        // gate-relative tile ids this wave owns (+8 for tj=1)
    auto step = [&](int t, int par) {
        // prefetch next step's x into the other buffer
        int tn2 = (t + 1 < TT) ? (t + 1) : (TT - 1);
        stage(tn2, par ^ 1);

        const unsigned short* xs = &xstage[par][0];

        // ---- phase A: z, r pre-activations (4 chains x 8 MFMA) ----
        f32x4 accA[4];
#pragma unroll
        for (int q = 0; q < 4; ++q) accA[q] = (f32x4){0.f, 0.f, 0.f, 0.f};
#pragma unroll
        for (int c = 0; c < 8; ++c) {
            short8 af = *(const short8*)&hA[nq][c * 32 + kq * 8];
#pragma unroll
            for (int q = 0; q < 4; ++q)
                accA[q] = __builtin_amdgcn_mfma_f32_16x16x32_bf16(
                    af, wzr[q][c], accA[q], 0, 0, 0);
        }

        float z[8];
#pragma unroll
        for (int tj = 0; tj < 2; ++tj) {   // z tiles
            int ti = tiz + 8 * tj;         // global tile = gate tile (z gate)
            ushort4 xv = *(const ushort4*)&xs[(ti * 64 + lane) * 4];
            unsigned short xa[4] = {xv.x, xv.y, xv.z, xv.w};
#pragma unroll
            for (int i = 0; i < 4; ++i) {
                float a = accA[tj][i] + bf2f(xa[i]);
                z[tj * 4 + i] = __builtin_amdgcn_fmed3f(
                    __builtin_fmaf(0.2f, a, 0.5f), 0.f, 1.f);
            }
        }
#pragma unroll
        for (int tj = 0; tj < 2; ++tj) {   // r tiles -> r*h into LDS
            int ti = 16 + tiz + 8 * tj;
            ushort4 xv = *(const ushort4*)&xs[(ti * 64 + lane) * 4];
            unsigned short xa[4] = {xv.x, xv.y, xv.z, xv.w};
            int col = (tiz + 8 * tj) * 16 + nq;
#pragma unroll
            for (int i = 0; i < 4; ++i) {
                float a = accA[2 + tj][i] + bf2f(xa[i]);
                float r = __builtin_amdgcn_fmed3f(
                    __builtin_fmaf(0.2f, a, 0.5f), 0.f, 1.f);
                rhA[kq * 4 + i][col] = (short)f2bf_fast(r * hprev[tj * 4 + i]);
            }
        }
        barrier_lgkm();

        // ---- phase B: candidate + state update (2 chains x 8 MFMA) ----
        f32x4 accH[2];
        accH[0] = (f32x4){0.f, 0.f, 0.f, 0.f};
        accH[1] = (f32x4){0.f, 0.f, 0.f, 0.f};
#pragma unroll
        for (int c = 0; c < 8; ++c) {
            short8 af = *(const short8*)&rhA[nq][c * 32 + kq * 8];
            accH[0] = __builtin_amdgcn_mfma_f32_16x16x32_bf16(af, wh[0][c], accH[0], 0, 0, 0);
            accH[1] = __builtin_amdgcn_mfma_f32_16x16x32_bf16(af, wh[1][c], accH[1], 0, 0, 0);
        }
#pragma unroll
        for (int tj = 0; tj < 2; ++tj) {
            int ti = 32 + tiz + 8 * tj;
            ushort4 xv = *(const ushort4*)&xs[(ti * 64 + lane) * 4];
            unsigned short xa[4] = {xv.x, xv.y, xv.z, xv.w};
            int col = (tiz + 8 * tj) * 16 + nq;
#pragma unroll
            for (int i = 0; i < 4; ++i) {
                float a = accH[tj][i] + bf2f(xa[i]);
                a = __builtin_amdgcn_fmed3f(a, -12.f, 12.f);
                float e  = exp2f(a * 2.88539008f);          // e^(2a)
                float hh = __builtin_fmaf(-2.f, __builtin_amdgcn_rcpf(e + 1.f), 1.f);
                int idx = tj * 4 + i;
                float hn = __builtin_fmaf(z[idx], hprev[idx] - hh, hh);
                hprev[idx] = hn;
                hA[kq * 4 + i][col] = (short)f2bf_fast(hn);
            }
        }
        barrier_full();   // drains this step's stage (issued ~1 step ago) + LDS
    };

    for (int t = 0; t < TT; t += 2) {
        step(t, 0);
        step(t + 1, 1);
    }

#pragma unroll
    for (int tj = 0; tj < 2; ++tj) {
        int col = (tiz + 8 * tj) * 16 + nq;
#pragma unroll
        for (int i = 0; i < 4; ++i)
            out[(size_t)(bid * 16 + kq * 4 + i) * HH + col] = hprev[tj * 4 + i];
    }
}

// ---------------------------------------------------------------------------
extern "C" void kernel_launch(void* const* d_in, const int* in_sizes, int n_in,
                              void* d_out, int out_size, void* d_ws, size_t ws_size,
                              hipStream_t stream) {
    const float* x  = (const float*)d_in[0];
    const float* Wz = (const float*)d_in[1];
    const float* Wr = (const float*)d_in[2];
    const float* Wh = (const float*)d_in[3];
    const float* Uz = (const float*)d_in[4];
    const float* Ur = (const float*)d_in[5];
    const float* Uh = (const float*)d_in[6];
    const float* bz = (const float*)d_in[7];
    const float* br = (const float*)d_in[8];
    const float* bh = (const float*)d_in[9];
    float* out = (float*)d_out;

    unsigned short* xw = (unsigned short*)d_ws;  // 192 MiB

    dim3 g1(NN3 / 64, MM / 64);  // 12 x 2048
    xproj_kernel<<<g1, 256, 0, stream>>>(x, Wz, Wr, Wh, bz, br, bh, xw);

    gru_rec_kernel<<<8, 512, 0, stream>>>(xw, Uz, Ur, Uh, out);
}

// Round 4
// 2978.855 us; speedup vs baseline: 3.0646x; 1.0874x over previous
//
#include <hip/hip_runtime.h>
#include <hip/hip_bf16.h>
#include <math.h>

// Problem constants
#define BB 128
#define TT 1024
#define DD 256
#define HH 256
#define MM (BB * TT)
#define NN3 768

typedef __attribute__((ext_vector_type(8))) short short8;
typedef __attribute__((ext_vector_type(4))) float f32x4;
typedef __attribute__((address_space(1))) unsigned int gu32;
typedef __attribute__((address_space(3))) unsigned int lu32;

static __device__ __forceinline__ float bf2f(unsigned int u16) {
    return __uint_as_float(u16 << 16);
}
// RNE
static __device__ __forceinline__ unsigned short f2bf(float f) {
    unsigned int u = __float_as_uint(f);
    unsigned int r = u + 0x7FFFu + ((u >> 16) & 1u);
    return (unsigned short)(r >> 16);
}
// round-half-up, 2 ops (per-step activations)
static __device__ __forceinline__ unsigned short f2bf_fast(float f) {
    return (unsigned short)((__float_as_uint(f) + 0x8000u) >> 16);
}

static __device__ __forceinline__ void barrier_lgkm() {
    asm volatile("s_waitcnt lgkmcnt(0)\n\ts_barrier" ::: "memory");
}
static __device__ __forceinline__ void barrier_full() {
    asm volatile("s_waitcnt vmcnt(0) lgkmcnt(0)\n\ts_barrier" ::: "memory");
}

// ---------------------------------------------------------------------------
// Kernel A: transpose+convert W -> Wb[768][256] bf16 (row n = gate*256+col,
// entries along k). One block per n-row.
// ---------------------------------------------------------------------------
__global__ __launch_bounds__(256) void wb_kernel(
    const float* __restrict__ Wz, const float* __restrict__ Wr,
    const float* __restrict__ Wh, unsigned short* __restrict__ Wb)
{
    int n = blockIdx.x;          // 0..767
    int g = n >> 8, col = n & 255;
    const float* W = (g == 0) ? Wz : (g == 1 ? Wr : Wh);
    int k = threadIdx.x;         // 0..255
    Wb[(size_t)n * 256 + k] = f2bf(W[(size_t)k * HH + col]);
}

// ---------------------------------------------------------------------------
// Kernel B: xproj via bf16 MFMA.  C = x[131072x256] @ Wcat[256x768] + bias,
// emitted as bf16 in the recurrence-native xw layout.
// Block: 128 m x 64 n, 256 threads (4 waves); wave wv owns rows wv*32..+32.
// W-fragments register-resident (loaded once per block from Wb).
// x loaded fp32 global -> VGPR -> bf16 fragments (no LDS).
// ---------------------------------------------------------------------------
__global__ __launch_bounds__(256)
__attribute__((amdgpu_waves_per_eu(2, 2)))
void xproj_mfma(
    const float* __restrict__ x, const unsigned short* __restrict__ Wb,
    const float* __restrict__ bz, const float* __restrict__ br,
    const float* __restrict__ bh, unsigned short* __restrict__ xw)
{
    const int tid  = threadIdx.x;
    const int lane = tid & 63;
    const int wv   = tid >> 6;
    const int nq   = lane & 15;
    const int kq   = lane >> 4;

    const int n0  = blockIdx.x * 64;   // 0..704
    const int m0  = blockIdx.y * 128;  // 0..130944
    const int g   = n0 >> 8;
    const int nc0 = n0 & 255;
    const float* bias = (g == 0) ? bz : (g == 1 ? br : bh);

    // persistent W fragments: [k-chunk c][n-subtile nt], 128 VGPRs
    short8 wf[8][4];
#pragma unroll
    for (int c = 0; c < 8; ++c)
#pragma unroll
        for (int nt = 0; nt < 4; ++nt)
            wf[c][nt] = *(const short8*)&Wb[(size_t)(n0 + nt * 16 + nq) * 256
                                            + c * 32 + kq * 8];
    float bv[4];
#pragma unroll
    for (int nt = 0; nt < 4; ++nt) bv[nt] = bias[nc0 + nt * 16 + nq];

    f32x4 acc[2][4];
#pragma unroll
    for (int mi = 0; mi < 2; ++mi)
#pragma unroll
        for (int nt = 0; nt < 4; ++nt) acc[mi][nt] = (f32x4){0.f, 0.f, 0.f, 0.f};

    const int mrow0 = m0 + wv * 32;

#pragma unroll
    for (int c = 0; c < 8; ++c) {
        short8 af[2];
#pragma unroll
        for (int mi = 0; mi < 2; ++mi) {
            const float* xp = &x[(size_t)(mrow0 + mi * 16 + nq) * 256
                                 + c * 32 + kq * 8];
            float4 f0 = *(const float4*)xp;
            float4 f1 = *(const float4*)(xp + 4);
            short8 a;
            a[0] = (short)f2bf(f0.x); a[1] = (short)f2bf(f0.y);
            a[2] = (short)f2bf(f0.z); a[3] = (short)f2bf(f0.w);
            a[4] = (short)f2bf(f1.x); a[5] = (short)f2bf(f1.y);
            a[6] = (short)f2bf(f1.z); a[7] = (short)f2bf(f1.w);
            af[mi] = a;
        }
#pragma unroll
        for (int mi = 0; mi < 2; ++mi)
#pragma unroll
            for (int nt = 0; nt < 4; ++nt)
                acc[mi][nt] = __builtin_amdgcn_mfma_f32_16x16x32_bf16(
                    af[mi], wf[c][nt], acc[mi][nt], 0, 0, 0);
    }

    // epilogue: +bias, bf16, scatter into recurrence layout
    const int t0   = (m0 & 1023) + wv * 32;
    const int b    = m0 >> 10;          // all 128 rows share the batch index
    const int bid  = b >> 4;
    const int brow = b & 15;
    const int lane4 = (brow >> 2) * 16 + nq;
    const int ii    = brow & 3;

#pragma unroll
    for (int mi = 0; mi < 2; ++mi)
#pragma unroll
        for (int nt = 0; nt < 4; ++nt) {
            int ti = g * 16 + (nc0 >> 4) + nt;
#pragma unroll
            for (int i = 0; i < 4; ++i) {
                int t = t0 + mi * 16 + kq * 4 + i;
                size_t addr = (size_t)(t * 8 + bid) * 12288
                              + (size_t)(ti * 256 + lane4 * 4 + ii);
                xw[addr] = f2bf(acc[mi][nt][i] + bv[nt]);
            }
        }
}

// ---------------------------------------------------------------------------
// Kernel C: persistent-register MFMA GRU recurrence.
// 8 blocks x 512 threads (8 waves, 2/SIMD -> 256 unified regs/wave).
// Changes vs R3: x loaded as MFMA C-operand init (no separate adds / no
// x-register prefetch lifetime), z-epilogue deferred into phase B so accH
// reuses accA[2..3]'s registers. Target: zero per-step spill.
// ---------------------------------------------------------------------------
__global__ __launch_bounds__(512)
__attribute__((amdgpu_waves_per_eu(2, 2)))
void gru_rec_kernel(
    const unsigned short* __restrict__ xw,
    const float* __restrict__ Uz, const float* __restrict__ Ur,
    const float* __restrict__ Uh,
    float* __restrict__ out)
{
    __shared__ unsigned short xstage[2][12288];  // 2 x 24576 B
    __shared__ short hA[16][264];    // h bf16, stride 132 dw
    __shared__ short rhA[16][264];   // r*h bf16

    const int tid  = threadIdx.x;
    const int lane = tid & 63;
    const int wv   = tid >> 6;
    const int nq   = lane & 15;
    const int kq   = lane >> 4;
    const int bid  = blockIdx.x;

    // ---- persistent weight fragments (192 regs/lane) ----
    short8 wzr[4][8];   // q 0,1 = Uz tiles {wv, wv+8}; q 2,3 = Ur tiles
#pragma unroll
    for (int q = 0; q < 4; ++q) {
        const float* U = (q < 2) ? Uz : Ur;
        const int col0 = (wv + 8 * (q & 1)) * 16;
#pragma unroll
        for (int c = 0; c < 8; ++c) {
            short8 f;
#pragma unroll
            for (int j = 0; j < 8; ++j)
                f[j] = (short)f2bf(U[(size_t)(c * 32 + kq * 8 + j) * HH + col0 + nq]);
            wzr[q][c] = f;
        }
    }
    short8 wh[2][8];
#pragma unroll
    for (int tj = 0; tj < 2; ++tj) {
        const int col0 = (wv + 8 * tj) * 16;
#pragma unroll
        for (int c = 0; c < 8; ++c) {
            short8 f;
#pragma unroll
            for (int j = 0; j < 8; ++j)
                f[j] = (short)f2bf(Uh[(size_t)(c * 32 + kq * 8 + j) * HH + col0 + nq]);
            wh[tj][c] = f;
        }
    }

    for (int idx = tid; idx < 16 * 264; idx += 512) ((short*)hA)[idx] = 0;
    float hprev[8];
#pragma unroll
    for (int i = 0; i < 8; ++i) hprev[i] = 0.f;

    auto stage = [&](int t, int buf) {
        const char* gsrc = (const char*)(xw + (size_t)(t * 8 + bid) * 12288);
        char* lbase = (char*)&xstage[buf][0];
        int woff = wv * 3072;
#pragma unroll
        for (int ld = 0; ld < 3; ++ld) {
            int off = woff + ld * 1024;
            __builtin_amdgcn_global_load_lds(
                (const gu32*)(gsrc + off + lane * 16),
                (lu32*)(lbase + off), 16, 0, 0);
        }
    };

    stage(0, 0);
    barrier_full();

    const int tiz = wv;
    auto step = [&](int t, int par) {
        int tn2 = (t + 1 < TT) ? (t + 1) : (TT - 1);
        stage(tn2, par ^ 1);

        const unsigned short* xs = &xstage[par][0];

        // ---- phase A: accA init = x (z,r), then MFMA chains over h ----
        f32x4 accA[4];
#pragma unroll
        for (int q = 0; q < 4; ++q) {
            int ti = (q < 2 ? 0 : 16) + tiz + 8 * (q & 1);
            uint2 u = *(const uint2*)&xs[(ti * 64 + lane) * 4];
            accA[q][0] = bf2f(u.x & 0xffffu);
            accA[q][1] = bf2f(u.x >> 16);
            accA[q][2] = bf2f(u.y & 0xffffu);
            accA[q][3] = bf2f(u.y >> 16);
        }
#pragma unroll
        for (int c = 0; c < 8; ++c) {
            short8 af = *(const short8*)&hA[nq][c * 32 + kq * 8];
#pragma unroll
            for (int q = 0; q < 4; ++q)
                accA[q] = __builtin_amdgcn_mfma_f32_16x16x32_bf16(
                    af, wzr[q][c], accA[q], 0, 0, 0);
        }

        // r epilogue only (z deferred to phase B)
#pragma unroll
        for (int tj = 0; tj < 2; ++tj) {
            int col = (tiz + 8 * tj) * 16 + nq;
#pragma unroll
            for (int i = 0; i < 4; ++i) {
                float r = __builtin_amdgcn_fmed3f(
                    __builtin_fmaf(0.2f, accA[2 + tj][i], 0.5f), 0.f, 1.f);
                rhA[kq * 4 + i][col] = (short)f2bf_fast(r * hprev[tj * 4 + i]);
            }
        }
        barrier_lgkm();

        // ---- phase B: accH init = xh, MFMA over r*h, z + h epilogue ----
        f32x4 accH[2];
#pragma unroll
        for (int tj = 0; tj < 2; ++tj) {
            int ti = 32 + tiz + 8 * tj;
            uint2 u = *(const uint2*)&xs[(ti * 64 + lane) * 4];
            accH[tj][0] = bf2f(u.x & 0xffffu);
            accH[tj][1] = bf2f(u.x >> 16);
            accH[tj][2] = bf2f(u.y & 0xffffu);
            accH[tj][3] = bf2f(u.y >> 16);
        }
#pragma unroll
        for (int c = 0; c < 8; ++c) {
            short8 af = *(const short8*)&rhA[nq][c * 32 + kq * 8];
            accH[0] = __builtin_amdgcn_mfma_f32_16x16x32_bf16(af, wh[0][c], accH[0], 0, 0, 0);
            accH[1] = __builtin_amdgcn_mfma_f32_16x16x32_bf16(af, wh[1][c], accH[1], 0, 0, 0);
        }

#pragma unroll
        for (int tj = 0; tj < 2; ++tj) {
            int col = (tiz + 8 * tj) * 16 + nq;
#pragma unroll
            for (int i = 0; i < 4; ++i) {
                int idx = tj * 4 + i;
                float z = __builtin_amdgcn_fmed3f(
                    __builtin_fmaf(0.2f, accA[tj][i], 0.5f), 0.f, 1.f);
                float a = __builtin_amdgcn_fmed3f(accH[tj][i], -12.f, 12.f);
                float e  = exp2f(a * 2.88539008f);          // e^(2a)
                float hh = __builtin_fmaf(-2.f, __builtin_amdgcn_rcpf(e + 1.f), 1.f);
                float hn = __builtin_fmaf(z, hprev[idx] - hh, hh);
                hprev[idx] = hn;
                hA[kq * 4 + i][col] = (short)f2bf_fast(hn);
            }
        }
        barrier_full();
    };

    for (int t = 0; t < TT; t += 2) {
        step(t, 0);
        step(t + 1, 1);
    }

#pragma unroll
    for (int tj = 0; tj < 2; ++tj) {
        int col = (tiz + 8 * tj) * 16 + nq;
#pragma unroll
        for (int i = 0; i < 4; ++i)
            out[(size_t)(bid * 16 + kq * 4 + i) * HH + col] = hprev[tj * 4 + i];
    }
}

// ---------------------------------------------------------------------------
extern "C" void kernel_launch(void* const* d_in, const int* in_sizes, int n_in,
                              void* d_out, int out_size, void* d_ws, size_t ws_size,
                              hipStream_t stream) {
    const float* x  = (const float*)d_in[0];
    const float* Wz = (const float*)d_in[1];
    const float* Wr = (const float*)d_in[2];
    const float* Wh = (const float*)d_in[3];
    const float* Uz = (const float*)d_in[4];
    const float* Ur = (const float*)d_in[5];
    const float* Uh = (const float*)d_in[6];
    const float* bz = (const float*)d_in[7];
    const float* br = (const float*)d_in[8];
    const float* bh = (const float*)d_in[9];
    float* out = (float*)d_out;

    // workspace: [xw: 192 MiB bf16][Wb: 768*256 bf16 = 384 KiB]
    unsigned short* xw = (unsigned short*)d_ws;
    unsigned short* Wb =
        (unsigned short*)((char*)d_ws + (size_t)MM * NN3 * sizeof(unsigned short));

    wb_kernel<<<NN3, 256, 0, stream>>>(Wz, Wr, Wh, Wb);

    dim3 g1(NN3 / 64, MM / 128);  // 12 x 1024
    xproj_mfma<<<g1, 256, 0, stream>>>(x, Wb, bz, br, bh, xw);

    gru_rec_kernel<<<8, 512, 0, stream>>>(xw, Uz, Ur, Uh, out);
}